// Round 12
// baseline (87.197 us; speedup 1.0000x reference)
//
#include <hip/hip_runtime.h>
#include <cstdint>

#define IN_FEAT 256
#define OUT_FEAT 64

constexpr int RPW = 4;              // rows per wave in scatter (~64 edges/wave)

typedef __attribute__((ext_vector_type(4))) float f32x4;
typedef __attribute__((ext_vector_type(8))) _Float16 f16x8;

union HF8 { _Float16 h[8]; f16x8 v; };

// ---------------------------------------------------------------------------
// Kernel 1: proj(fp16) = feat @ W via mfma_f32_16x16x32_f16, PLUS building
// row_ptr[0..n_rows] (CSR offsets) from the sorted adj_rows under the shadow
// of the pinned 16-deep feat load batch. row_ptr[r] = first edge index with
// row >= r (gap-filled for empty rows); row_ptr[n_rows] = n_edges.
// W staged in LDS pre-packed into B-fragment layout (validated round 8):
//   sWh[((ks*4+ct)*64 + l)*8 + j] = f16(W[ks*32 + (l>>4)*8 + j][ct*16+(l&15)])
// Block = 256 thr = 4 waves, each wave one 16-row x 64-col tile.
// No out-zeroing here: the row-partitioned scatter writes every row once.
// ---------------------------------------------------------------------------
__global__ __launch_bounds__(256) void gemm_proj_mfma(
    const float* __restrict__ feat, const float* __restrict__ W,
    _Float16* __restrict__ projh, const int* __restrict__ rows,
    int* __restrict__ row_ptr, int n_rows, int n_edges)
{
    __shared__ _Float16 sWh[8 * 4 * 64 * 8];   // 16384 fp16 = 32 KB

    const int lane = threadIdx.x & 63;
    const int wave = threadIdx.x >> 6;
    const int row0 = blockIdx.x * 64 + wave * 16;
    const int kgrp = lane >> 4;            // 0..3
    int ar = row0 + (lane & 15);           // this lane's A row
    if (ar >= n_rows) ar = n_rows - 1;     // clamp; stores are guarded

    // Phase A: issue the full feat row-chunk (16 dwordx4) and pin the batch.
    f32x4 fa[16];
    const float* fp = feat + (size_t)ar * IN_FEAT + kgrp * 8;
    #pragma unroll
    for (int ks = 0; ks < 8; ++ks) {
        fa[2 * ks]     = *reinterpret_cast<const f32x4*>(fp + ks * 32);
        fa[2 * ks + 1] = *reinterpret_cast<const f32x4*>(fp + ks * 32 + 4);
    }
    __builtin_amdgcn_sched_barrier(0);     // keep all 16 loads issued here

    // Phase A': CSR row_ptr build (hides under the feat loads). ~4 edges/thr.
    {
        const int tid  = blockIdx.x * 256 + threadIdx.x;
        const int nthr = gridDim.x * 256;
        for (int e = tid; e < n_edges; e += nthr) {
            const int r = rows[e];
            if (e == 0) {
                for (int q = 0; q <= r; ++q) row_ptr[q] = 0;
            } else {
                const int rp = rows[e - 1];
                for (int q = rp + 1; q <= r; ++q) row_ptr[q] = e;
            }
            if (e == n_edges - 1) {
                for (int q = r + 1; q <= n_rows; ++q) row_ptr[q] = n_edges;
            }
        }
    }

    // Phase B: W -> fp16, packed to B-frag layout (coalesced, L2-hot).
    {
        const int c   = threadIdx.x & 63;        // W column (coalesced axis)
        const int kg0 = threadIdx.x >> 6;        // k-group 0..3 within iter
        #pragma unroll
        for (int it = 0; it < 8; ++it) {
            const int kg = it * 4 + kg0;         // k-group 0..31 (k = kg*8+j)
            HF8 tmp;
            #pragma unroll
            for (int j = 0; j < 8; ++j)
                tmp.h[j] = (_Float16)W[(kg * 8 + j) * OUT_FEAT + c];
            const int ks = kg >> 2;
            const int l  = (kg & 3) * 16 + (c & 15);
            const int ct = c >> 4;
            *reinterpret_cast<f16x8*>(&sWh[((ks * 4 + ct) * 64 + l) * 8]) = tmp.v;
        }
    }
    __syncthreads();
    if (row0 >= n_rows) return;            // after barrier: uniform participation

    f32x4 acc[4];
    #pragma unroll
    for (int ct = 0; ct < 4; ++ct) acc[ct] = f32x4{0.f, 0.f, 0.f, 0.f};

    #pragma unroll
    for (int ks = 0; ks < 8; ++ks) {
        HF8 A;
        #pragma unroll
        for (int h = 0; h < 2; ++h) {
            const f32x4 v = fa[2 * ks + h];
            #pragma unroll
            for (int j = 0; j < 4; ++j)
                A.h[h * 4 + j] = (_Float16)v[j];   // compiler packs: v_cvt_pk
        }
        #pragma unroll
        for (int ct = 0; ct < 4; ++ct) {
            HF8 B;
            B.v = *reinterpret_cast<const f16x8*>(
                &sWh[((ks * 4 + ct) * 64 + lane) * 8]);
            acc[ct] = __builtin_amdgcn_mfma_f32_16x16x32_f16(A.v, B.v, acc[ct], 0, 0, 0);
        }
    }

    #pragma unroll
    for (int r = 0; r < 4; ++r) {
        const int row = row0 + kgrp * 4 + r;
        if (row < n_rows) {
            #pragma unroll
            for (int ct = 0; ct < 4; ++ct)
                projh[(size_t)row * OUT_FEAT + ct * 16 + (lane & 15)] =
                    (_Float16)acc[ct][r];
        }
    }
}

// ---------------------------------------------------------------------------
// Kernel 2: out[row] = sum(val * proj[col]) over that row's edges.
// ROW-PARTITIONED, RPW=4: wave w exclusively owns rows [4w, 4w+4) -- 25000
// waves (same parallelism as the validated round-8 edge-partition), expected
// ~64 edges/wave so the batch loop usually runs ONCE. Edge range
// [row_ptr[r0], row_ptr[r1]) processed in 64-edge batches: coalesced
// metadata preload, 64 static-readlane gathers pinned as a batch, segmented
// register accumulate. Every flush is a PLAIN STORE (no atomics anywhere);
// empty rows zero-filled via a 4-bit flushed mask. One write per out element.
// ---------------------------------------------------------------------------
__global__ __launch_bounds__(256) void gather_scatter(
    const _Float16* __restrict__ projh, const int* __restrict__ rows,
    const int* __restrict__ cols, const float* __restrict__ vals,
    const int* __restrict__ row_ptr, float* __restrict__ out, int n_rows)
{
    const int lane = threadIdx.x & 63;
    const int wid  = (blockIdx.x * 256 + threadIdx.x) >> 6;
    const int r0 = wid * RPW;
    if (r0 >= n_rows) return;
    const int r1 = min(r0 + RPW, n_rows);

    const int e_begin = row_ptr[r0];           // uniform scalar loads
    const int e_end   = row_ptr[r1];

    unsigned flushed = 0;                      // bit j -> row r0+j written

    if (e_begin < e_end) {
        float acc = 0.f;
        int cur = rows[e_begin];               // >= r0, < r1 by construction
        for (int b = e_begin; b < e_end; b += 64) {       // uniform trip
            const int rem = e_end - b;                     // > 0
            const int ee = (lane < rem) ? (b + lane) : (e_end - 1);
            const int r_v = rows[ee];
            const int c_v = cols[ee];
            const int v_bits = (lane < rem)
                                 ? __builtin_bit_cast(int, vals[ee]) : 0;

            // Issue all 64 gathers, pinned as a batch (full MLP).
            _Float16 p[64];
            #pragma unroll
            for (int i = 0; i < 64; ++i) {
                const int c = __builtin_amdgcn_readlane(c_v, i);   // SGPR
                p[i] = projh[(size_t)c * OUT_FEAT + lane];
            }
            __builtin_amdgcn_sched_barrier(0);

            // Segmented accumulate; flush = plain store (row wholly owned).
            // Clamped tail lanes have r == rows[e_end-1] == cur and v == 0.
            #pragma unroll
            for (int i = 0; i < 64; ++i) {
                const int   r = __builtin_amdgcn_readlane(r_v, i);  // SGPR
                const float v = __builtin_bit_cast(float,
                                    __builtin_amdgcn_readlane(v_bits, i));
                if (r != cur) {                                     // uniform
                    out[(size_t)cur * OUT_FEAT + lane] = acc;
                    flushed |= 1u << (cur - r0);
                    acc = 0.f;
                    cur = r;
                }
                acc = fmaf(v, (float)p[i], acc);
            }
        }
        out[(size_t)cur * OUT_FEAT + lane] = acc;          // final row
        flushed |= 1u << (cur - r0);
    }

    // Zero-fill rows with no edges (out is poisoned, must be 0).
    #pragma unroll
    for (int j = 0; j < RPW; ++j) {
        if (r0 + j < n_rows && !(flushed & (1u << j)))
            out[(size_t)(r0 + j) * OUT_FEAT + lane] = 0.f;
    }
}

extern "C" void kernel_launch(void* const* d_in, const int* in_sizes, int n_in,
                              void* d_out, int out_size, void* d_ws, size_t ws_size,
                              hipStream_t stream)
{
    const float* feat     = (const float*)d_in[0];
    const float* weight   = (const float*)d_in[1];
    const int*   adj_rows = (const int*)d_in[2];
    const int*   adj_cols = (const int*)d_in[3];
    const float* adj_vals = (const float*)d_in[4];
    float*       out      = (float*)d_out;

    const int n_nodes = in_sizes[0] / IN_FEAT;   // 100000
    const int n_edges = in_sizes[2];             // 1600000

    _Float16* projh   = (_Float16*)d_ws;                       // 12.8 MB
    int*      row_ptr = (int*)((char*)d_ws +
                        (size_t)n_nodes * OUT_FEAT * sizeof(_Float16));

    const int gemm_blocks = (n_nodes + 63) / 64;
    gemm_proj_mfma<<<gemm_blocks, 256, 0, stream>>>(feat, weight, projh,
                                                    adj_rows, row_ptr,
                                                    n_nodes, n_edges);

    const int waves  = (n_nodes + RPW - 1) / RPW;
    const int blocks = (waves + 3) / 4;
    gather_scatter<<<blocks, 256, 0, stream>>>(projh, adj_rows, adj_cols,
                                               adj_vals, row_ptr, out,
                                               n_nodes);
}

// Round 13
// 64.476 us; speedup vs baseline: 1.3524x; 1.3524x over previous
//
#include <hip/hip_runtime.h>
#include <cstdint>

#define IN_FEAT 256
#define OUT_FEAT 64

constexpr int EPW = 64;             // edges per wave in scatter (1 per lane)

typedef __attribute__((ext_vector_type(4))) float f32x4;
typedef __attribute__((ext_vector_type(8))) _Float16 f16x8;

union HF8 { _Float16 h[8]; f16x8 v; };

// ---------------------------------------------------------------------------
// Kernel 1 (round-8 validated, unchanged): proj(fp16) = feat @ W via
// mfma_f32_16x16x32_f16, plus zeroing of `out` (folded memset).
// Feat loads issued 16-deep and pinned with sched_barrier(0).
// W staged in LDS pre-packed into B-fragment layout:
//   sWh[((ks*4+ct)*64 + l)*8 + j] = f16(W[ks*32 + (l>>4)*8 + j][ct*16+(l&15)])
// Block = 256 thr = 4 waves, each wave one 16-row x 64-col tile.
// ---------------------------------------------------------------------------
__global__ __launch_bounds__(256) void gemm_proj_mfma(
    const float* __restrict__ feat, const float* __restrict__ W,
    _Float16* __restrict__ projh, float* __restrict__ out, int n_rows)
{
    __shared__ _Float16 sWh[8 * 4 * 64 * 8];   // 16384 fp16 = 32 KB

    const int lane = threadIdx.x & 63;
    const int wave = threadIdx.x >> 6;
    const int row0 = blockIdx.x * 64 + wave * 16;
    const int kgrp = lane >> 4;            // 0..3
    int ar = row0 + (lane & 15);           // this lane's A row
    if (ar >= n_rows) ar = n_rows - 1;     // clamp; stores are guarded

    // Phase A: issue the full feat row-chunk (16 dwordx4) and pin the batch.
    f32x4 fa[16];
    const float* fp = feat + (size_t)ar * IN_FEAT + kgrp * 8;
    #pragma unroll
    for (int ks = 0; ks < 8; ++ks) {
        fa[2 * ks]     = *reinterpret_cast<const f32x4*>(fp + ks * 32);
        fa[2 * ks + 1] = *reinterpret_cast<const f32x4*>(fp + ks * 32 + 4);
    }
    __builtin_amdgcn_sched_barrier(0);     // keep all 16 loads issued here

    // Phase B: W -> fp16, packed to B-frag layout (coalesced, L2-hot).
    {
        const int c   = threadIdx.x & 63;        // W column (coalesced axis)
        const int kg0 = threadIdx.x >> 6;        // k-group 0..3 within iter
        #pragma unroll
        for (int it = 0; it < 8; ++it) {
            const int kg = it * 4 + kg0;         // k-group 0..31 (k = kg*8+j)
            HF8 tmp;
            #pragma unroll
            for (int j = 0; j < 8; ++j)
                tmp.h[j] = (_Float16)W[(kg * 8 + j) * OUT_FEAT + c];
            const int ks = kg >> 2;
            const int l  = (kg & 3) * 16 + (c & 15);
            const int ct = c >> 4;
            *reinterpret_cast<f16x8*>(&sWh[((ks * 4 + ct) * 64 + l) * 8]) = tmp.v;
        }
    }
    __syncthreads();
    if (row0 >= n_rows) return;            // after barrier: uniform participation

    f32x4 acc[4];
    #pragma unroll
    for (int ct = 0; ct < 4; ++ct) acc[ct] = f32x4{0.f, 0.f, 0.f, 0.f};

    #pragma unroll
    for (int ks = 0; ks < 8; ++ks) {
        HF8 A;
        #pragma unroll
        for (int h = 0; h < 2; ++h) {
            const f32x4 v = fa[2 * ks + h];
            #pragma unroll
            for (int j = 0; j < 4; ++j)
                A.h[h * 4 + j] = (_Float16)v[j];   // compiler packs: v_cvt_pk
        }
        #pragma unroll
        for (int ct = 0; ct < 4; ++ct) {
            HF8 B;
            B.v = *reinterpret_cast<const f16x8*>(
                &sWh[((ks * 4 + ct) * 64 + lane) * 8]);
            acc[ct] = __builtin_amdgcn_mfma_f32_16x16x32_f16(A.v, B.v, acc[ct], 0, 0, 0);
        }
    }

    #pragma unroll
    for (int r = 0; r < 4; ++r) {
        const int row = row0 + kgrp * 4 + r;
        if (row < n_rows) {
            #pragma unroll
            for (int ct = 0; ct < 4; ++ct)
                projh[(size_t)row * OUT_FEAT + ct * 16 + (lane & 15)] =
                    (_Float16)acc[ct][r];
        }
    }

    // Folded memset: zero this wave's 16 out-rows (4 coalesced 256B bursts).
    #pragma unroll
    for (int i = 0; i < 4; ++i) {
        const int row = row0 + i * 4 + (lane >> 4);
        if (row < n_rows)
            *reinterpret_cast<f32x4*>(
                out + (size_t)row * OUT_FEAT + (lane & 15) * 4) =
                f32x4{0.f, 0.f, 0.f, 0.f};
    }
}

// ---------------------------------------------------------------------------
// Kernel 2: out[row] += val * proj[col] over sorted-by-row COO edges.
// Round-8 edge-partitioned structure (validated) + two VALU cuts:
//  (a) segment-boundary BALLOT MASK: row-change tests become compile-time
//      SGPR bit tests; readlane(r) only at actual boundaries (~4/chunk vs 64)
//  (b) scalar cols: readfirstlane-pinned uniform base + compile-time offsets
//      -> s_load path for gather addresses (removes 64 readlane(c)).
// v stays on the validated vector-load + readlane path. Interior segments
// exclusively owned (rows sorted) -> plain store onto the gemm-zeroed out;
// first + final flush use atomicAdd. Tail chunks take the round-8 slow path.
// ---------------------------------------------------------------------------
__global__ __launch_bounds__(256) void gather_scatter(
    const _Float16* __restrict__ projh, const int* __restrict__ rows,
    const int* __restrict__ cols, const float* __restrict__ vals,
    float* __restrict__ out, int n_edges)
{
    const int lane = threadIdx.x & 63;
    const long wid = (long)((blockIdx.x * 256 + threadIdx.x) >> 6);
    const long e0 = wid * EPW;
    if (e0 >= n_edges) return;

    if (e0 + EPW <= n_edges) {
        // ---- fast path: full 64-edge chunk ----
        const int e0u = __builtin_amdgcn_readfirstlane((int)e0);
        const int*   rp = rows + e0u;
        const int*   cp = cols + e0u;         // uniform base -> scalar loads
        const float* vp = vals + e0u;

        const int r_v = rp[lane];                          // coalesced vector
        const int v_bits = __builtin_bit_cast(int, vp[lane]);
        const int r_prev = __shfl_up(r_v, 1);
        const unsigned long long mask =
            __ballot(lane > 0 && r_v != r_prev);           // SGPR pair

        // Issue all 64 gathers, pinned as a batch (full MLP).
        _Float16 p[EPW];
        #pragma unroll
        for (int i = 0; i < EPW; ++i) {
            const int c = cp[i];                           // uniform -> SGPR
            p[i] = projh[(size_t)c * OUT_FEAT + lane];
        }
        __builtin_amdgcn_sched_barrier(0);

        float acc = 0.f;
        int cur = __builtin_amdgcn_readlane(r_v, 0);
        bool first_seg = true;                             // uniform
        #pragma unroll
        for (int i = 0; i < EPW; ++i) {
            if (mask & (1ull << i)) {                      // SALU bit test
                float* dst = out + (size_t)cur * OUT_FEAT + lane;
                if (first_seg) atomicAdd(dst, acc);        // may span waves
                else           *dst = acc;                 // exclusive row
                first_seg = false;
                acc = 0.f;
                cur = __builtin_amdgcn_readlane(r_v, i);   // boundaries only
            }
            const float v = __builtin_bit_cast(float,
                                __builtin_amdgcn_readlane(v_bits, i));
            acc = fmaf(v, (float)p[i], acc);
        }
        atomicAdd(out + (size_t)cur * OUT_FEAT + lane, acc);
    } else {
        // ---- slow path: tail chunk (round-8 clamped readlane version) ----
        const long ee = (e0 + lane < n_edges) ? (e0 + lane) : (n_edges - 1);
        const int r_v = rows[ee];
        const int c_v = cols[ee];
        const int v_bits = (e0 + lane < n_edges)
                             ? __builtin_bit_cast(int, vals[ee]) : 0;

        _Float16 p[EPW];
        #pragma unroll
        for (int i = 0; i < EPW; ++i) {
            const int c = __builtin_amdgcn_readlane(c_v, i);
            p[i] = projh[(size_t)c * OUT_FEAT + lane];
        }
        __builtin_amdgcn_sched_barrier(0);

        float acc = 0.f;
        int cur = __builtin_amdgcn_readlane(r_v, 0);
        bool first_seg = true;
        #pragma unroll
        for (int i = 0; i < EPW; ++i) {
            const int   r = __builtin_amdgcn_readlane(r_v, i);
            const float v = __builtin_bit_cast(float,
                                __builtin_amdgcn_readlane(v_bits, i));
            if (r != cur) {
                float* dst = out + (size_t)cur * OUT_FEAT + lane;
                if (first_seg) atomicAdd(dst, acc);
                else           *dst = acc;
                first_seg = false;
                acc = 0.f;
                cur = r;
            }
            acc = fmaf(v, (float)p[i], acc);
        }
        atomicAdd(out + (size_t)cur * OUT_FEAT + lane, acc);
    }
}

extern "C" void kernel_launch(void* const* d_in, const int* in_sizes, int n_in,
                              void* d_out, int out_size, void* d_ws, size_t ws_size,
                              hipStream_t stream)
{
    const float* feat     = (const float*)d_in[0];
    const float* weight   = (const float*)d_in[1];
    const int*   adj_rows = (const int*)d_in[2];
    const int*   adj_cols = (const int*)d_in[3];
    const float* adj_vals = (const float*)d_in[4];
    float*       out      = (float*)d_out;
    _Float16*    projh    = (_Float16*)d_ws;   // n_nodes*64*2 = 12.8 MB

    const int n_nodes = in_sizes[0] / IN_FEAT;   // 100000
    const int n_edges = in_sizes[2];             // 1600000

    const int gemm_blocks = (n_nodes + 63) / 64;
    gemm_proj_mfma<<<gemm_blocks, 256, 0, stream>>>(feat, weight, projh, out,
                                                    n_nodes);

    const int waves  = (n_edges + EPW - 1) / EPW;
    const int blocks = (waves + 3) / 4;
    gather_scatter<<<blocks, 256, 0, stream>>>(projh, adj_rows, adj_cols,
                                               adj_vals, out, n_edges);
}

// Round 14
// 60.990 us; speedup vs baseline: 1.4297x; 1.0571x over previous
//
#include <hip/hip_runtime.h>
#include <cstdint>

#define IN_FEAT 256
#define OUT_FEAT 64

constexpr int EPW = 64;             // edges per wave in scatter (1 per lane)

typedef __attribute__((ext_vector_type(4))) float f32x4;
typedef __attribute__((ext_vector_type(8))) _Float16 f16x8;

union HF8 { _Float16 h[8]; f16x8 v; };

// ---------------------------------------------------------------------------
// Kernel 1: proj(fp16) = feat @ W via mfma_f32_16x16x32_f16, plus zeroing of
// `out` (folded memset, coalesced 1 KB per wave).
// The sched_barrier(0) after the 16-deep feat load batch keeps all 16
// dwordx4 in flight under the W-pack prologue (round-4 counters showed the
// compiler otherwise sinks loads to their converts: VGPR=44, ~3.3 TB/s).
// W staged in LDS pre-packed into B-fragment layout:
//   sWh[((ks*4+ct)*64 + l)*8 + j] = f16(W[ks*32 + (l>>4)*8 + j][ct*16+(l&15)])
// Block = 256 thr = 4 waves, each wave one 16-row x 64-col tile.
// [best-measured configuration: 61.5 us total -- round 8]
// ---------------------------------------------------------------------------
__global__ __launch_bounds__(256) void gemm_proj_mfma(
    const float* __restrict__ feat, const float* __restrict__ W,
    _Float16* __restrict__ projh, float* __restrict__ out, int n_rows)
{
    __shared__ _Float16 sWh[8 * 4 * 64 * 8];   // 16384 fp16 = 32 KB

    const int lane = threadIdx.x & 63;
    const int wave = threadIdx.x >> 6;
    const int row0 = blockIdx.x * 64 + wave * 16;
    const int kgrp = lane >> 4;            // 0..3
    int ar = row0 + (lane & 15);           // this lane's A row
    if (ar >= n_rows) ar = n_rows - 1;     // clamp; stores are guarded

    // Phase A: issue the full feat row-chunk (16 dwordx4) and PIN the batch.
    f32x4 fa[16];
    const float* fp = feat + (size_t)ar * IN_FEAT + kgrp * 8;
    #pragma unroll
    for (int ks = 0; ks < 8; ++ks) {
        fa[2 * ks]     = *reinterpret_cast<const f32x4*>(fp + ks * 32);
        fa[2 * ks + 1] = *reinterpret_cast<const f32x4*>(fp + ks * 32 + 4);
    }
    __builtin_amdgcn_sched_barrier(0);     // keep all 16 loads issued here

    // Phase B: W -> fp16, packed to B-frag layout (coalesced, L2-hot).
    {
        const int c   = threadIdx.x & 63;        // W column (coalesced axis)
        const int kg0 = threadIdx.x >> 6;        // k-group 0..3 within iter
        #pragma unroll
        for (int it = 0; it < 8; ++it) {
            const int kg = it * 4 + kg0;         // k-group 0..31 (k = kg*8+j)
            HF8 tmp;
            #pragma unroll
            for (int j = 0; j < 8; ++j)
                tmp.h[j] = (_Float16)W[(kg * 8 + j) * OUT_FEAT + c];
            const int ks = kg >> 2;
            const int l  = (kg & 3) * 16 + (c & 15);
            const int ct = c >> 4;
            *reinterpret_cast<f16x8*>(&sWh[((ks * 4 + ct) * 64 + l) * 8]) = tmp.v;
        }
    }
    __syncthreads();
    if (row0 >= n_rows) return;            // after barrier: uniform participation

    f32x4 acc[4];
    #pragma unroll
    for (int ct = 0; ct < 4; ++ct) acc[ct] = f32x4{0.f, 0.f, 0.f, 0.f};

    #pragma unroll
    for (int ks = 0; ks < 8; ++ks) {
        HF8 A;
        #pragma unroll
        for (int h = 0; h < 2; ++h) {
            const f32x4 v = fa[2 * ks + h];
            #pragma unroll
            for (int j = 0; j < 4; ++j)
                A.h[h * 4 + j] = (_Float16)v[j];   // compiler packs: v_cvt_pk
        }
        #pragma unroll
        for (int ct = 0; ct < 4; ++ct) {
            HF8 B;
            B.v = *reinterpret_cast<const f16x8*>(
                &sWh[((ks * 4 + ct) * 64 + lane) * 8]);
            acc[ct] = __builtin_amdgcn_mfma_f32_16x16x32_f16(A.v, B.v, acc[ct], 0, 0, 0);
        }
    }

    #pragma unroll
    for (int r = 0; r < 4; ++r) {
        const int row = row0 + kgrp * 4 + r;
        if (row < n_rows) {
            #pragma unroll
            for (int ct = 0; ct < 4; ++ct)
                projh[(size_t)row * OUT_FEAT + ct * 16 + (lane & 15)] =
                    (_Float16)acc[ct][r];
        }
    }

    // Folded memset: zero this wave's 16 out-rows (4 coalesced 256B bursts).
    #pragma unroll
    for (int i = 0; i < 4; ++i) {
        const int row = row0 + i * 4 + (lane >> 4);
        if (row < n_rows)
            *reinterpret_cast<f32x4*>(
                out + (size_t)row * OUT_FEAT + (lane & 15) * 4) =
                f32x4{0.f, 0.f, 0.f, 0.f};
    }
}

// ---------------------------------------------------------------------------
// Kernel 2: out[row] += val * proj[col]  over sorted-by-row COO edges.
// One wave owns 64 contiguous edges; lane = feature column.
// Phase 1: coalesced metadata preload, then fully static-unrolled gather of
// all 64 fp16 proj rows into p[64] (compile-time readlane -> SGPR col ->
// 64 independent 128B-contiguous loads, pinned as a batch with
// sched_barrier(0) so the compiler can't sink them to their fmas).
// Phase 2: segmented register accumulation with SGPR row compares. Interior
// segments are exclusively owned (rows sorted) -> plain store onto the
// gemm-zeroed out; first + final flush use atomicAdd (may span waves).
// [best-measured configuration: 61.5 us total -- round 8]
// ---------------------------------------------------------------------------
__global__ __launch_bounds__(256) void gather_scatter(
    const _Float16* __restrict__ projh, const int* __restrict__ rows,
    const int* __restrict__ cols, const float* __restrict__ vals,
    float* __restrict__ out, int n_edges)
{
    const int lane = threadIdx.x & 63;
    const long wid = (long)((blockIdx.x * 256 + threadIdx.x) >> 6);
    const long e0 = wid * EPW;
    if (e0 >= n_edges) return;

    const long ee = (e0 + lane < n_edges) ? (e0 + lane) : (n_edges - 1);
    const int r_v = rows[ee];
    const int c_v = cols[ee];
    const int v_bits = (e0 + lane < n_edges)
                         ? __builtin_bit_cast(int, vals[ee]) : 0;

    // Phase 1: issue all 64 gathers, pinned as a batch.
    _Float16 p[EPW];
    #pragma unroll
    for (int i = 0; i < EPW; ++i) {
        const int c = __builtin_amdgcn_readlane(c_v, i);   // SGPR
        p[i] = projh[(size_t)c * OUT_FEAT + lane];
    }
    __builtin_amdgcn_sched_barrier(0);

    // Phase 2: segmented accumulate + flush.
    float acc = 0.f;
    int cur = __builtin_amdgcn_readlane(r_v, 0);
    bool first_seg = true;                                  // uniform
    #pragma unroll
    for (int i = 0; i < EPW; ++i) {
        const int   r = __builtin_amdgcn_readlane(r_v, i);  // SGPR
        const float v = __builtin_bit_cast(float, __builtin_amdgcn_readlane(v_bits, i));
        if (r != cur) {                                     // scalar, uniform
            float* dst = out + (size_t)cur * OUT_FEAT + lane;
            if (first_seg) atomicAdd(dst, acc);             // may span waves
            else           *dst = acc;                      // exclusive row
            first_seg = false;
            acc = 0.f;
            cur = r;
        }
        acc = fmaf(v, (float)p[i], acc);
    }
    atomicAdd(out + (size_t)cur * OUT_FEAT + lane, acc);    // may span waves
}

extern "C" void kernel_launch(void* const* d_in, const int* in_sizes, int n_in,
                              void* d_out, int out_size, void* d_ws, size_t ws_size,
                              hipStream_t stream)
{
    const float* feat     = (const float*)d_in[0];
    const float* weight   = (const float*)d_in[1];
    const int*   adj_rows = (const int*)d_in[2];
    const int*   adj_cols = (const int*)d_in[3];
    const float* adj_vals = (const float*)d_in[4];
    float*       out      = (float*)d_out;
    _Float16*    projh    = (_Float16*)d_ws;   // n_nodes*64*2 = 12.8 MB

    const int n_nodes = in_sizes[0] / IN_FEAT;   // 100000
    const int n_edges = in_sizes[2];             // 1600000

    const int gemm_blocks = (n_nodes + 63) / 64;
    gemm_proj_mfma<<<gemm_blocks, 256, 0, stream>>>(feat, weight, projh, out,
                                                    n_nodes);

    const int waves  = (n_edges + EPW - 1) / EPW;
    const int blocks = (waves + 3) / 4;
    gather_scatter<<<blocks, 256, 0, stream>>>(projh, adj_rows, adj_cols,
                                               adj_vals, out, n_edges);
}